// Round 6
// baseline (56.041 us; speedup 1.0000x reference)
//
#include <hip/hip_runtime.h>
#include <hip/hip_bf16.h>
#include <math.h>

// R6: ABLATION ROUND + improved fused kernel.
//   dispatch 1: prep_wfrag (weights -> per-lane A-frag layout)
//   dispatch 2: abl_compute  -- R5's compute phase ONLY (reg-filled LDS, no
//               x/depth global loads, no strided out stores). Its dur_us in
//               the profile isolates the compute/wf-load latency chain.
//   dispatch 3: dconv_fused2 -- improved real kernel (128px strip, 2x work
//               per wave, paired-b32 stage writes, launch_bounds(256,4)).

#define ALPHA_F 8.3f

constexpr int B_    = 4;
constexpr int CIN   = 32;
constexpr int COUT  = 32;
constexpr int H_    = 256;
constexpr int W_    = 256;
constexpr int KTAPS = 9;
constexpr int HW    = H_ * W_;

typedef __attribute__((ext_vector_type(8))) short bf16x8;
typedef __attribute__((ext_vector_type(4))) float f32x4;

static __device__ __forceinline__ short f2bf(float f) {
    __hip_bfloat16 h = __float2bfloat16(f);
    return __builtin_bit_cast(short, h);
}

// ---- prep: weights into per-lane A-fragment layout (verified R2-R5) ----
__global__ void prep_wfrag(const float* __restrict__ w, short* __restrict__ wf) {
    int idx = blockIdx.x * 256 + threadIdx.x;
    if (idx >= KTAPS * 2 * 64 * 8) return;
    int e  = idx & 7;
    int l  = (idx >> 3) & 63;
    int t  = (idx >> 9) & 1;
    int ij = idx >> 10;
    int o  = t * 16 + (l & 15);
    int c  = (l >> 4) * 8 + e;
    wf[idx] = f2bf(w[(o * CIN + c) * KTAPS + ij]);
}

// ---- ABLATION: R5 compute phase only ----
// Same grid (4096x256), same LDS shapes, same per-tap structure (2 global wf
// loads + 1 ds_read_b128 + 2 MFMA + 8 fmac + exp-based sims). LDS filled from
// registers (vectorized, ~zero cost); one dword store per thread keeps all
// results live (rule #17: no DCE).
__global__ __launch_bounds__(256)
void abl_compute(const short* __restrict__ wf, float* __restrict__ wsout) {
    __shared__ short xs[3][66][40];
    __shared__ float dsh[3][66];

    const int bid   = (int)blockIdx.x;
    const int strip = (bid & 7) * 512 + (bid >> 3);
    const int h     = (strip >> 2) & 255;
    const int wseg  = (strip & 3) << 6;
    const int tid   = threadIdx.x;

    // cheap reg->LDS fill (b64 vectorized, linear: conflict-free)
    {
        ushort4* xsv = (ushort4*)&xs[0][0][0];     // 3*66*40/4 = 1980 chunks
#pragma unroll
        for (int it = 0; it < 8; ++it) {
            const int idx = it * 256 + tid;
            if (idx < 1980) {
                const unsigned short a =
                    (unsigned short)f2bf((float)(idx & 63) * 0.01f);
                const unsigned short b =
                    (unsigned short)f2bf((float)((idx >> 2) & 63) * 0.02f);
                ushort4 v; v.x = a; v.y = b; v.z = a; v.w = b;
                xsv[idx] = v;
            }
        }
        if (tid < 198) {
            const int r = tid / 66, q = tid - r * 66;
            dsh[r][q] = (float)q * 0.003f + (float)r * 0.01f;
        }
    }
    __syncthreads();

    const int lane = tid & 63;
    const int warp = tid >> 6;
    const int n    = lane & 15;
    const int cg   = (lane >> 4) * 8;
    const int pl   = warp * 16 + n + 1;
    const int wp   = wseg + warp * 16 + n;

    const float dc = dsh[1][pl];

    float s[KTAPS];
#pragma unroll
    for (int ij = 0; ij < KTAPS; ++ij) {
        const int di = ij / 3 - 1;
        const int dj = ij % 3 - 1;
        const bool ok = ((unsigned)(h + di) < (unsigned)H_) &&
                        ((unsigned)(wp + dj) < (unsigned)W_);
        const float dp = dsh[1 + di][pl + dj];
        s[ij] = ok ? __expf(-ALPHA_F * fabsf(dc - dp)) : 0.f;
    }

    const bf16x8* wfv = (const bf16x8*)wf;
    f32x4 acc0 = {0.f, 0.f, 0.f, 0.f};
    f32x4 acc1 = {0.f, 0.f, 0.f, 0.f};
    const f32x4 z = {0.f, 0.f, 0.f, 0.f};
#pragma unroll
    for (int ij = 0; ij < KTAPS; ++ij) {
        const int di = ij / 3 - 1;
        const int dj = ij % 3 - 1;
        const bf16x8 bfrag = *(const bf16x8*)&xs[1 + di][pl + dj][cg];
        const bf16x8 a0 = wfv[(ij * 2 + 0) * 64 + lane];
        const bf16x8 a1 = wfv[(ij * 2 + 1) * 64 + lane];
        const f32x4 t0 = __builtin_amdgcn_mfma_f32_16x16x32_bf16(a0, bfrag, z, 0, 0, 0);
        const f32x4 t1 = __builtin_amdgcn_mfma_f32_16x16x32_bf16(a1, bfrag, z, 0, 0, 0);
#pragma unroll
        for (int j = 0; j < 4; ++j) {
            acc0[j] = fmaf(s[ij], t0[j], acc0[j]);
            acc1[j] = fmaf(s[ij], t1[j], acc1[j]);
        }
    }

    const float red = acc0[0] + acc0[1] + acc0[2] + acc0[3] +
                      acc1[0] + acc1[1] + acc1[2] + acc1[3];
    wsout[bid * 256 + tid] = red;   // 4 MB scratch, keeps everything live
}

// ---- improved real kernel: 128-px strip, 2 subtiles per wave ----
__global__ __launch_bounds__(256, 4)
void dconv_fused2(const float* __restrict__ x,
                  const float* __restrict__ depth,
                  const short* __restrict__ wf,
                  float* __restrict__ out) {
    __shared__ short xs[3][130][40];   // 31,200 B (40: 80B px stride, 16B-aligned b128)
    __shared__ float dsh[3][130];      //  1,560 B

    // XCD-aware bijective swizzle (2048 blocks, 2048 % 8 == 0)
    const int bid  = (int)blockIdx.x;
    const int bswz = (bid & 7) * 256 + (bid >> 3);

    const int b    = bswz >> 9;          // 512 strips per image
    const int h    = (bswz >> 1) & 255;
    const int wseg = (bswz & 1) << 7;    // 128-px segment base

    const int tid = threadIdx.x;
    const float* xb  = x + (size_t)b * CIN * HW;
    const float* dpl = depth + (size_t)b * HW;

    // ---- stage: channel-PAIR per thread -> one b32 LDS write ----
    // main: 3 rows x 16 ch-pairs x 128 px = 6144 pairs = 24 iters
#pragma unroll
    for (int it = 0; it < 24; ++it) {
        const int idx = it * 256 + tid;
        const int q   = idx & 127;
        const int rc  = idx >> 7;        // 0..47
        const int cp  = rc & 15;
        const int r   = rc >> 4;
        const int row = h + r - 1;
        const bool ok = ((unsigned)row < (unsigned)H_);
        const size_t gb = (size_t)(2 * cp) * HW + row * W_ + wseg + q;
        const float f0 = ok ? xb[gb]      : 0.f;
        const float f1 = ok ? xb[gb + HW] : 0.f;
        const int v = (int)(unsigned short)f2bf(f0) |
                      ((int)(unsigned short)f2bf(f1) << 16);
        ((int*)&xs[r][q + 1][0])[cp] = v;
    }
    // halo: 2 edge px x 3 rows x 16 pairs = 96
    if (tid < 96) {
        const int side = tid & 1;
        const int rc   = tid >> 1;       // 0..47
        const int cp   = rc & 15;
        const int r    = rc >> 4;
        const int row  = h + r - 1;
        const int wx   = wseg - 1 + side * 129;
        const int ql   = side * 129;
        const bool ok  = ((unsigned)row < (unsigned)H_) &&
                         ((unsigned)wx  < (unsigned)W_);
        const size_t gb = (size_t)(2 * cp) * HW + row * W_ + wx;
        const float f0 = ok ? xb[gb]      : 0.f;
        const float f1 = ok ? xb[gb + HW] : 0.f;
        const int v = (int)(unsigned short)f2bf(f0) |
                      ((int)(unsigned short)f2bf(f1) << 16);
        ((int*)&xs[r][ql][0])[cp] = v;
    }
    // depth stencil: 3 x 130 = 390
    for (int k = tid; k < 390; k += 256) {
        const int r   = k / 130;
        const int q   = k - r * 130;
        const int row = h + r - 1;
        const int wx  = wseg - 1 + q;
        const bool ok = ((unsigned)row < (unsigned)H_) &&
                        ((unsigned)wx  < (unsigned)W_);
        dsh[r][q] = ok ? dpl[row * W_ + wx] : 0.f;
    }
    __syncthreads();

    // ---- compute: each wave owns 32 px = 2 MFMA subtiles ----
    const int lane = tid & 63;
    const int warp = tid >> 6;
    const int n    = lane & 15;
    const int cg   = (lane >> 4) * 8;
    const int pl0  = warp * 32 + n + 1;
    const int pl1  = pl0 + 16;
    const int wp0  = wseg + warp * 32 + n;
    const int wp1  = wp0 + 16;

    const float dc0 = dsh[1][pl0];
    const float dc1 = dsh[1][pl1];

    float s0[KTAPS], s1[KTAPS];
#pragma unroll
    for (int ij = 0; ij < KTAPS; ++ij) {
        const int di = ij / 3 - 1;
        const int dj = ij % 3 - 1;
        const bool okh = ((unsigned)(h + di) < (unsigned)H_);
        const bool ok0 = okh && ((unsigned)(wp0 + dj) < (unsigned)W_);
        const bool ok1 = okh && ((unsigned)(wp1 + dj) < (unsigned)W_);
        s0[ij] = ok0 ? __expf(-ALPHA_F * fabsf(dc0 - dsh[1 + di][pl0 + dj])) : 0.f;
        s1[ij] = ok1 ? __expf(-ALPHA_F * fabsf(dc1 - dsh[1 + di][pl1 + dj])) : 0.f;
    }

    const bf16x8* wfv = (const bf16x8*)wf;
    f32x4 a00 = {0.f,0.f,0.f,0.f}, a01 = {0.f,0.f,0.f,0.f};
    f32x4 a10 = {0.f,0.f,0.f,0.f}, a11 = {0.f,0.f,0.f,0.f};
    const f32x4 z = {0.f, 0.f, 0.f, 0.f};

#pragma unroll
    for (int ij = 0; ij < KTAPS; ++ij) {
        const int di = ij / 3 - 1;
        const int dj = ij % 3 - 1;
        const bf16x8 wa0 = wfv[(ij * 2 + 0) * 64 + lane];
        const bf16x8 wa1 = wfv[(ij * 2 + 1) * 64 + lane];
        const bf16x8 b0  = *(const bf16x8*)&xs[1 + di][pl0 + dj][cg];
        const bf16x8 b1  = *(const bf16x8*)&xs[1 + di][pl1 + dj][cg];
        const f32x4 t0 = __builtin_amdgcn_mfma_f32_16x16x32_bf16(wa0, b0, z, 0, 0, 0);
        const f32x4 t1 = __builtin_amdgcn_mfma_f32_16x16x32_bf16(wa1, b0, z, 0, 0, 0);
        const f32x4 t2 = __builtin_amdgcn_mfma_f32_16x16x32_bf16(wa0, b1, z, 0, 0, 0);
        const f32x4 t3 = __builtin_amdgcn_mfma_f32_16x16x32_bf16(wa1, b1, z, 0, 0, 0);
#pragma unroll
        for (int j = 0; j < 4; ++j) {
            a00[j] = fmaf(s0[ij], t0[j], a00[j]);
            a01[j] = fmaf(s0[ij], t1[j], a01[j]);
            a10[j] = fmaf(s1[ij], t2[j], a10[j]);
            a11[j] = fmaf(s1[ij], t3[j], a11[j]);
        }
    }

    // C/D layout: col(pixel) = lane&15, row(o') = (lane>>4)*4 + reg
    const int orow = (lane >> 4) * 4;
    float* ob0 = out + (size_t)b * COUT * HW + h * W_ + wp0;
    float* ob1 = out + (size_t)b * COUT * HW + h * W_ + wp1;
#pragma unroll
    for (int j = 0; j < 4; ++j) {
        ob0[(orow + j) * HW]      = a00[j];
        ob0[(orow + j + 16) * HW] = a01[j];
        ob1[(orow + j) * HW]      = a10[j];
        ob1[(orow + j + 16) * HW] = a11[j];
    }
}

// ---------- fp32 fallback (R1 kernel) ----------
__global__ __launch_bounds__(256)
void dconv_fallback(const float* __restrict__ x,
                    const float* __restrict__ depth,
                    const float* __restrict__ wgt,
                    float* __restrict__ out) {
    const int w  = threadIdx.x;
    const int bh = blockIdx.x;
    const int b  = bh >> 8;
    const int h  = bh & 255;

    const float* dplane = depth + (size_t)b * HW;
    const float  dc     = dplane[h * W_ + w];

    float acc[COUT];
#pragma unroll
    for (int o = 0; o < COUT; ++o) acc[o] = 0.f;

    const float* xb = x + (size_t)b * CIN * HW;

    for (int i = 0; i < 3; ++i) {
        const int  hh  = h + i - 1;
        const bool okh = ((unsigned)hh < (unsigned)H_);
        for (int j = 0; j < 3; ++j) {
            const int  ww = w + j - 1;
            const bool ok = okh && ((unsigned)ww < (unsigned)W_);
            const int  ij = i * 3 + j;
            const float dpv = ok ? dplane[hh * W_ + ww] : 0.f;
            const float sv  = __expf(-ALPHA_F * fabsf(dc - dpv));
            const int base = hh * W_ + ww;
#pragma unroll
            for (int c = 0; c < CIN; ++c) {
                const float v = (ok ? xb[c * HW + base] : 0.f) * sv;
#pragma unroll
                for (int o = 0; o < COUT; ++o) {
                    acc[o] = fmaf(v, wgt[(o * CIN + c) * KTAPS + ij], acc[o]);
                }
            }
        }
    }

    float* ob = out + ((size_t)b * COUT * H_ + h) * W_ + w;
#pragma unroll
    for (int o = 0; o < COUT; ++o) ob[o * HW] = acc[o];
}

extern "C" void kernel_launch(void* const* d_in, const int* in_sizes, int n_in,
                              void* d_out, int out_size, void* d_ws, size_t ws_size,
                              hipStream_t stream) {
    const float* x     = (const float*)d_in[0];
    const float* depth = (const float*)d_in[1];
    const float* wgt   = (const float*)d_in[2];
    float*       out   = (float*)d_out;

    // ws layout: [0, 18KB) wf | [1MB, 5MB) ablation scratch
    if (ws_size >= (size_t)(5u << 20)) {
        short* wf    = (short*)d_ws;
        float* wsabl = (float*)((char*)d_ws + (1u << 20));
        prep_wfrag<<<(KTAPS * 2 * 64 * 8 + 255) / 256, 256, 0, stream>>>(wgt, wf);
        abl_compute<<<4096, 256, 0, stream>>>(wf, wsabl);
        dconv_fused2<<<2048, 256, 0, stream>>>(x, depth, wf, out);
    } else {
        dconv_fallback<<<B_ * H_, 256, 0, stream>>>(x, depth, wgt, out);
    }
}